// Round 10
// baseline (170.751 us; speedup 1.0000x reference)
//
#include <hip/hip_runtime.h>
#include <math.h>

#define M_ 4
#define A_ 256
#define RBF_ 64
#define F_ 32
#define H_ 32
#define SI_ 32
#define TF_ 128   // 4 tags * F
#define SASTRIDE 158   // shorts; 79 dwords (odd) -> a-frag reads 2-way max (free)

typedef __attribute__((ext_vector_type(8))) short bf16x8;
typedef __attribute__((ext_vector_type(4))) float f32x4;
typedef __attribute__((ext_vector_type(3))) float f32x3;

__device__ __forceinline__ unsigned short f2bf(float f) {
  union { float f; unsigned u; } v; v.f = f;
  unsigned r = v.u + 0x7FFFu + ((v.u >> 16) & 1u);   // RNE bf16 (weights, one-time)
  return (unsigned short)(r >> 16);
}

// pack two fp32 -> two bf16 (round-half-up: +0x8000 then take hi16) in 3 VALU
__device__ __forceinline__ unsigned pack2bf(float lo, float hi) {
  union { float f; unsigned u; } a, b; a.f = lo; b.f = hi;
  return __builtin_amdgcn_perm(b.u + 0x8000u, a.u + 0x8000u, 0x07060302u);
}

__device__ __forceinline__ float sspf(float x) {
  // log(0.5*exp(x)+0.5) = softplus(x) - ln2, numerically stable
  return fmaxf(x, 0.f) + log1pf(expf(-fabsf(x))) - 0.6931471805599453f;
}

// ---------------------------------------------------------------------------
// Setup: collapse the two linear Dense layers per tag into one 64x32 map.
// ws layout: WcT bf16 [tf=128][k=64] (16384 B) | bc fp32[128] at +16384
//            | part fp32 [1024][2][352] at +32768 (2.88 MB).
// tf = tag*32 + f, tag order {00,01,10,11}.
// ---------------------------------------------------------------------------
__global__ __launch_bounds__(256) void combine_weights(
    const float* __restrict__ w1_00, const float* __restrict__ b1_00,
    const float* __restrict__ w2_00, const float* __restrict__ b2_00,
    const float* __restrict__ w1_01, const float* __restrict__ b1_01,
    const float* __restrict__ w2_01, const float* __restrict__ b2_01,
    const float* __restrict__ w1_10, const float* __restrict__ b1_10,
    const float* __restrict__ w2_10, const float* __restrict__ b2_10,
    const float* __restrict__ w1_11, const float* __restrict__ b1_11,
    const float* __restrict__ w2_11, const float* __restrict__ b2_11,
    unsigned short* __restrict__ wsT, float* __restrict__ bcw)
{
  const float* w1s[4] = {w1_00, w1_01, w1_10, w1_11};
  const float* b1s[4] = {b1_00, b1_01, b1_10, b1_11};
  const float* w2s[4] = {w2_00, w2_01, w2_10, w2_11};
  const float* b2s[4] = {b2_00, b2_01, b2_10, b2_11};
  int tid = blockIdx.x * 256 + threadIdx.x;    // 0..8191
  int k   = tid >> 7;
  int tf  = tid & 127;
  int tag = tf >> 5, f = tf & 31;
  const float* w1 = w1s[tag];
  const float* w2 = w2s[tag];
  float s = 0.f;
  for (int h = 0; h < H_; ++h) s += w1[k * H_ + h] * w2[h * F_ + f];
  wsT[tf * 64 + k] = f2bf(s);                  // transposed for B-frag loads
  if (tid < TF_) {
    const float* b1 = b1s[tag];
    const float* b2 = b2s[tag];
    float sb = b2[f];
    for (int h = 0; h < H_; ++h) sb += b1[h] * w2[h * F_ + f];
    bcw[tf] = sb;                              // bias stays fp32
  }
}

// ---------------------------------------------------------------------------
// Partial-conv kernel: one block per (m,a,half) -- grid 2048, 512 thr, 8 waves.
//  WAVE-PER-TAG (R8): wave wu owns ONE ct = tag*2+which tf-tile.
//  NEW (R10): ILP-2 -- two independent accumulation chains per wave
//  (chain0 = btiles 0..3, chain1 = btiles 4..7, bodies alternate), so one
//  chain's ds_read->MFMA->contract latency is covered by the other's issue.
//  Each chain single-buffered; the alternation gives a free one-body (~250cy)
//  prefetch lead.
//  LDS pad is RA-strategy: 41984 B -> 3 blocks/CU by LDS -> compiler targets
//  6 waves/SIMD -> VGPR budget ~85 (fits ~70 live, no spill). At R8's 20 KB
//  the RA would target 8 waves/SIMD (64 cap) and spill the second chain
//  (R7's failure mode). Stride 158 shorts = 79 dwords (odd) also cuts the
//  a-frag ds_read_b128 bank conflicts from 8-way to 2-way (free, m136).
//  GEMM via mfma_f32_16x16x32_bf16; C-frag row(b)=quad*4+reg, col=lane&15.
//  Quad-copy reduce via shfl_xor; partials (352/half) to ws; si_epilogue sums.
// ---------------------------------------------------------------------------
__global__ __launch_bounds__(512, 4) void conv_partial(
    const float* __restrict__ image, const float* __restrict__ vectors,
    const float* __restrict__ feat0, const float* __restrict__ feat1,
    const unsigned short* __restrict__ wsT, const float* __restrict__ bcw,
    float* __restrict__ part)
{
  __shared__ __align__(16) unsigned short sA[128 * SASTRIDE];  // 40448 B
  __shared__ float sV[128 * 3];                                // 1536 B

  const int t    = threadIdx.x;
  const int bid  = blockIdx.x;
  const int ma   = bid >> 1;        // m*256 + a
  const int half = bid & 1;
  const int m    = ma >> 8;
  const int l    = t & 63;
  const int n    = l & 15;
  const int quad = l >> 4;
  // wave id as SGPR -> uniform branches
  const int wu    = __builtin_amdgcn_readfirstlane(t >> 6);   // 0..7
  const int which = wu & 1;
  const int tag   = wu >> 1;        // 0:'00' 1:'01' 2:'10' 3:'11'
  const int ct    = tag * 2 + which;
  const int f     = which * 16 + n; // feature column this lane owns

  // ---- Wc fragment + bias into registers (global, L2-resident) ----
  const unsigned short* wr = wsT + (ct * 16 + n) * 64 + quad * 8;
  const bf16x8 w0 = *(const bf16x8*)(wr);
  const bf16x8 w1 = *(const bf16x8*)(wr + 32);
  const float  bc = bcw[ct * 16 + n];

  // ---- stage this half's image rows (128 b x 64 rbf) to LDS as bf16 ----
  const float* imgH = image + ((size_t)ma * A_ + half * 128) * RBF_;
  #pragma unroll
  for (int i = 0; i < 2; ++i) {
    int g = t + 512 * i;            // 0..1023 groups of 8 elems
    int r = g >> 3, c8 = g & 7;
    const float* src = imgH + r * RBF_ + c8 * 8;
    float4 v0 = *(const float4*)(src);
    float4 v1 = *(const float4*)(src + 4);
    uint4 pk;
    pk.x = pack2bf(v0.x, v0.y);
    pk.y = pack2bf(v0.z, v0.w);
    pk.z = pack2bf(v1.x, v1.y);
    pk.w = pack2bf(v1.z, v1.w);
    *(uint4*)&sA[r * SASTRIDE + c8 * 8] = pk;
  }
  // ---- stage vectors (128 b x 3) to LDS ----
  if (t < 384) sV[t] = vectors[((size_t)ma * A_ + half * 128) * 3 + t];

  // lane-private feat pointers (global b)
  const float* p0 = feat0 + (size_t)(m * A_) * F_ + f;          // + b*F_
  const float* p1 = feat1 + ((size_t)(m * A_) * F_ + f) * 3;    // + b*96

  // two chains, single-buffered operands each (tag<=1 uses gx only, as feat0)
  float gxA[4], gyA[4], gzA[4];
  float gxB[4], gyB[4], gzB[4];
  float pA = 0.f, pB0 = 0.f, pB1 = 0.f, pB2 = 0.f;

#define PF(GX, GY, GZ, BT) { \
    const int b0 = half * 128 + (BT) * 16 + quad * 4; \
    if (tag <= 1) { \
      _Pragma("unroll") \
      for (int r = 0; r < 4; ++r) GX[r] = p0[(b0 + r) * F_]; \
    } else { \
      _Pragma("unroll") \
      for (int r = 0; r < 4; ++r) { \
        f32x3 v = *(const f32x3*)&p1[(size_t)(b0 + r) * (F_ * 3)]; \
        GX[r] = v[0]; GY[r] = v[1]; GZ[r] = v[2]; \
      } \
    } }

#define BODY(BT, GX, GY, GZ) { \
    const int brow = (BT) * 16; \
    const int lb   = brow + quad * 4; \
    const bf16x8 a0 = *(const bf16x8*)&sA[(brow + n) * SASTRIDE + quad * 8]; \
    const bf16x8 a1 = *(const bf16x8*)&sA[(brow + n) * SASTRIDE + 32 + quad * 8]; \
    f32x4 acc = {bc, bc, bc, bc}; \
    acc = __builtin_amdgcn_mfma_f32_16x16x32_bf16(a0, w0, acc, 0, 0, 0); \
    acc = __builtin_amdgcn_mfma_f32_16x16x32_bf16(a1, w1, acc, 0, 0, 0); \
    if (tag == 0) {            /* out_0x0_0 */ \
      _Pragma("unroll") \
      for (int r = 0; r < 4; ++r) pA += acc[r] * GX[r]; \
    } else if (tag == 1) {     /* out_0x1_1 = v * (R*feat0) */ \
      _Pragma("unroll") \
      for (int r = 0; r < 4; ++r) { \
        const float s  = acc[r] * GX[r]; \
        pB0 += sV[(lb + r) * 3 + 0] * s; \
        pB1 += sV[(lb + r) * 3 + 1] * s; \
        pB2 += sV[(lb + r) * 3 + 2] * s; \
      } \
    } else if (tag == 2) {     /* out_1x0_1 = R * feat1 */ \
      _Pragma("unroll") \
      for (int r = 0; r < 4; ++r) { \
        const float Rr = acc[r]; \
        pB0 += Rr * GX[r]; pB1 += Rr * GY[r]; pB2 += Rr * GZ[r]; \
      } \
    } else {                   /* out_1x1_0 (dot) + out_1x1_1 (cross) */ \
      _Pragma("unroll") \
      for (int r = 0; r < 4; ++r) { \
        const float Rr = acc[r]; \
        const float ax = GX[r], ay = GY[r], az = GZ[r]; \
        const float vx = sV[(lb + r) * 3 + 0]; \
        const float vy = sV[(lb + r) * 3 + 1]; \
        const float vz = sV[(lb + r) * 3 + 2]; \
        pA  += Rr * (vx * ax + vy * ay + vz * az); \
        pB0 += Rr * (vy * az - vz * ay); \
        pB1 += Rr * (vz * ax - vx * az); \
        pB2 += Rr * (vx * ay - vy * ax); \
      } \
    } }

  PF(gxA, gyA, gzA, 0)     // chain0 first tile
  PF(gxB, gyB, gzB, 4)     // chain1 first tile
  __syncthreads();

  #pragma unroll 1
  for (int it = 0; it < 4; ++it) {
    BODY(it, gxA, gyA, gzA)
    if (it < 3) PF(gxA, gyA, gzA, it + 1)      // ~1-body lead via alternation
    BODY(4 + it, gxB, gyB, gzB)
    if (it < 3) PF(gxB, gyB, gzB, 4 + it + 1)
  }

  // ---- reduce the 4 quad-copies via cross-lane butterfly, write partials ----
#define QRED(x) { x += __shfl_xor(x, 16); x += __shfl_xor(x, 32); }
  QRED(pA) QRED(pB0) QRED(pB1) QRED(pB2)
  if (quad == 0) {
    float* dst = part + ((size_t)ma * 2 + half) * 352;
    // slots (cat order): out000: f | out110: 32+f | out011: 64+f*3+d
    //                    out101: 160+f*3+d | out111: 256+f*3+d
    if (tag == 0) {
      dst[f] = pA;
    } else if (tag == 1) {
      f32x3 v = {pB0, pB1, pB2};
      *(f32x3*)&dst[64 + f * 3] = v;
    } else if (tag == 2) {
      f32x3 v = {pB0, pB1, pB2};
      *(f32x3*)&dst[160 + f * 3] = v;
    } else {
      dst[32 + f] = pA;
      f32x3 v = {pB0, pB1, pB2};
      *(f32x3*)&dst[256 + f * 3] = v;
    }
  }
}

// ---------------------------------------------------------------------------
// Epilogue: one block per (m,a), 64 threads. Sum the two halves' partials,
// then self-interaction + equivariant activation.
// ---------------------------------------------------------------------------
__global__ __launch_bounds__(64) void si_epilogue(
    const float* __restrict__ part,
    const float* __restrict__ w_si0, const float* __restrict__ w_si1,
    const float* __restrict__ b_act0, const float* __restrict__ b_act1,
    float* __restrict__ out)
{
  __shared__ float cat[352];
  const int ma = blockIdx.x;
  const int t  = threadIdx.x;
  const float* pA = part + (size_t)ma * 704;
  const float* pB = pA + 352;
  for (int s = t; s < 352; s += 64) cat[s] = pA[s] + pB[s];
  __syncthreads();

  const int outBase = ma * SI_;
  if (t < 32) {
    const float* wr = w_si0 + t * 64;
    float s = 0.f;
    #pragma unroll 8
    for (int ff = 0; ff < 64; ++ff) s += cat[ff] * wr[ff];
    s += b_act0[t];
    out[outBase + t] = sspf(s);
  } else {
    int g = t - 32;
    const float* wr = w_si1 + g * 96;
    float s0 = 0.f, s1 = 0.f, s2 = 0.f;
    #pragma unroll 8
    for (int ff = 0; ff < 96; ++ff) {
      float wv = wr[ff];
      s0 += cat[64 + ff * 3 + 0] * wv;
      s1 += cat[64 + ff * 3 + 1] * wv;
      s2 += cat[64 + ff * 3 + 2] * wv;
    }
    float n2 = s0 * s0 + s1 * s1 + s2 * s2;
    float n1 = sqrtf(fmaxf(n2, 1e-7f));     // norm_with_epsilon, EPS=1e-7
    float a1 = sspf(n1 + b_act1[g]);
    float sc = a1 / n1;
    int ob = M_ * A_ * SI_ + (outBase + g) * 3;   // o0 is 32768 floats
    out[ob + 0] = s0 * sc;
    out[ob + 1] = s1 * sc;
    out[ob + 2] = s2 * sc;
  }
}

extern "C" void kernel_launch(void* const* d_in, const int* in_sizes, int n_in,
                              void* d_out, int out_size, void* d_ws, size_t ws_size,
                              hipStream_t stream) {
  const float* image   = (const float*)d_in[0];
  const float* vectors = (const float*)d_in[1];
  const float* feat0   = (const float*)d_in[2];
  const float* feat1   = (const float*)d_in[3];
  const float* w_si0   = (const float*)d_in[20];
  const float* w_si1   = (const float*)d_in[21];
  const float* b_act0  = (const float*)d_in[22];
  const float* b_act1  = (const float*)d_in[23];
  unsigned short* wsT = (unsigned short*)d_ws;           // 128*64 bf16 = 16384 B
  float* bcw  = (float*)((char*)d_ws + 16384);           // 128 f32
  float* part = (float*)((char*)d_ws + 32768);           // 1024*2*352 f32
  float* out  = (float*)d_out;

  combine_weights<<<32, 256, 0, stream>>>(
      (const float*)d_in[4],  (const float*)d_in[5],
      (const float*)d_in[6],  (const float*)d_in[7],
      (const float*)d_in[8],  (const float*)d_in[9],
      (const float*)d_in[10], (const float*)d_in[11],
      (const float*)d_in[12], (const float*)d_in[13],
      (const float*)d_in[14], (const float*)d_in[15],
      (const float*)d_in[16], (const float*)d_in[17],
      (const float*)d_in[18], (const float*)d_in[19],
      wsT, bcw);

  conv_partial<<<2 * M_ * A_, 512, 0, stream>>>(
      image, vectors, feat0, feat1, wsT, bcw, part);

  si_epilogue<<<M_ * A_, 64, 0, stream>>>(
      part, w_si0, w_si1, b_act0, b_act1, out);
}

// Round 11
// 161.301 us; speedup vs baseline: 1.0586x; 1.0586x over previous
//
#include <hip/hip_runtime.h>
#include <math.h>

#define M_ 4
#define A_ 256
#define RBF_ 64
#define F_ 32
#define H_ 32
#define SI_ 32
#define TF_ 128   // 4 tags * F

typedef __attribute__((ext_vector_type(8))) short bf16x8;
typedef __attribute__((ext_vector_type(4))) float f32x4;
typedef __attribute__((ext_vector_type(3))) float f32x3;

__device__ __forceinline__ unsigned short f2bf(float f) {
  union { float f; unsigned u; } v; v.f = f;
  unsigned r = v.u + 0x7FFFu + ((v.u >> 16) & 1u);   // RNE bf16 (weights, one-time)
  return (unsigned short)(r >> 16);
}

// pack two fp32 -> two bf16 (round-half-up: +0x8000 then take hi16) in 3 VALU
__device__ __forceinline__ unsigned pack2bf(float lo, float hi) {
  union { float f; unsigned u; } a, b; a.f = lo; b.f = hi;
  return __builtin_amdgcn_perm(b.u + 0x8000u, a.u + 0x8000u, 0x07060302u);
}

__device__ __forceinline__ float sspf(float x) {
  // log(0.5*exp(x)+0.5) = softplus(x) - ln2, numerically stable
  return fmaxf(x, 0.f) + log1pf(expf(-fabsf(x))) - 0.6931471805599453f;
}

// ---------------------------------------------------------------------------
// Setup: collapse the two linear Dense layers per tag into one 64x32 map.
// ws layout: WcT bf16 [tf=128][k=64] (16384 B) | bc fp32[128] at +16384
//            | part fp32 [1024][2][352] at +32768 (2.88 MB).
// tf = tag*32 + f, tag order {00,01,10,11}.
// ---------------------------------------------------------------------------
__global__ __launch_bounds__(256) void combine_weights(
    const float* __restrict__ w1_00, const float* __restrict__ b1_00,
    const float* __restrict__ w2_00, const float* __restrict__ b2_00,
    const float* __restrict__ w1_01, const float* __restrict__ b1_01,
    const float* __restrict__ w2_01, const float* __restrict__ b2_01,
    const float* __restrict__ w1_10, const float* __restrict__ b1_10,
    const float* __restrict__ w2_10, const float* __restrict__ b2_10,
    const float* __restrict__ w1_11, const float* __restrict__ b1_11,
    const float* __restrict__ w2_11, const float* __restrict__ b2_11,
    unsigned short* __restrict__ wsT, float* __restrict__ bcw)
{
  const float* w1s[4] = {w1_00, w1_01, w1_10, w1_11};
  const float* b1s[4] = {b1_00, b1_01, b1_10, b1_11};
  const float* w2s[4] = {w2_00, w2_01, w2_10, w2_11};
  const float* b2s[4] = {b2_00, b2_01, b2_10, b2_11};
  int tid = blockIdx.x * 256 + threadIdx.x;    // 0..8191
  int k   = tid >> 7;
  int tf  = tid & 127;
  int tag = tf >> 5, f = tf & 31;
  const float* w1 = w1s[tag];
  const float* w2 = w2s[tag];
  float s = 0.f;
  for (int h = 0; h < H_; ++h) s += w1[k * H_ + h] * w2[h * F_ + f];
  wsT[tf * 64 + k] = f2bf(s);                  // transposed for B-frag loads
  if (tid < TF_) {
    const float* b1 = b1s[tag];
    const float* b2 = b2s[tag];
    float sb = b2[f];
    for (int h = 0; h < H_; ++h) sb += b1[h] * w2[h * F_ + f];
    bcw[tf] = sb;                              // bias stays fp32
  }
}

// ---------------------------------------------------------------------------
// Partial-conv kernel: one block per (m,a,half) -- grid 2048, 512 thr, 8 waves.
//  WAVE-PER-TAG (R8 base, its best measured config: 44 VGPR, 4 blocks/CU).
//  R11 changes vs R8:
//   (1) role = (wu + (bid&3)*2) & 7 : rotates tag roles across SIMDs per
//       block so resident blocks balance the heavy tag3 waves (R8 pinned
//       tag3 to SIMD 2/3 -> systematic 2x imbalance).
//   (2) Address strength-reduction: one running base pointer per stream
//       (a-frags, feat0/feat1, sV), advanced by a constant per iteration;
//       all per-body accesses are immediate offsets. R8 recomputed
//       (brow+n)*72 muls + 64-bit feat addresses per body -> ~750 VALU
//       inst/wave measured (VALUBusy 23% x 42.5us = 9.8us issue). Target ~40% cut.
//   (3) stride back to 72 (R10's 158 pad DOUBLED conflicts; conflicts are
//       4% of cycles -- not the bottleneck).
//  GEMM via mfma_f32_16x16x32_bf16; C-frag row(b)=quad*4+reg, col=lane&15.
//  Quad-copy reduce via shfl_xor; partials (352/half) to ws; si_epilogue sums.
// LDS: sA [128][72] bf16 (18432) + sV [384] f32 (1536) = 19968 B.
// DO NOT raise min-waves (R6: hard 64-cap spill = 1.3 GB scratch traffic).
// Spill sentinel: WRITE_SIZE must stay ~2.8 MB (partials only).
// ---------------------------------------------------------------------------
__global__ __launch_bounds__(512, 4) void conv_partial(
    const float* __restrict__ image, const float* __restrict__ vectors,
    const float* __restrict__ feat0, const float* __restrict__ feat1,
    const unsigned short* __restrict__ wsT, const float* __restrict__ bcw,
    float* __restrict__ part)
{
  __shared__ __align__(16) unsigned short sA[128 * 72];   // 18432 B
  __shared__ float sV[128 * 3];                           // 1536 B

  const int t    = threadIdx.x;
  const int bid  = blockIdx.x;
  const int ma   = bid >> 1;        // m*256 + a
  const int half = bid & 1;
  const int m    = ma >> 8;
  const int l    = t & 63;
  const int n    = l & 15;
  const int quad = l >> 4;
  // wave id as SGPR -> uniform branches; rotate roles across SIMDs per block
  const int wu    = __builtin_amdgcn_readfirstlane(t >> 6);   // 0..7
  const int role  = (wu + ((bid & 3) << 1)) & 7;
  const int which = role & 1;
  const int tag   = role >> 1;      // 0:'00' 1:'01' 2:'10' 3:'11'
  const int ct    = tag * 2 + which;
  const int f     = which * 16 + n; // feature column this lane owns

  // ---- Wc fragment + bias into registers (global, L2-resident) ----
  const unsigned short* wr = wsT + (ct * 16 + n) * 64 + quad * 8;
  const bf16x8 w0 = *(const bf16x8*)(wr);
  const bf16x8 w1 = *(const bf16x8*)(wr + 32);
  const float  bc = bcw[ct * 16 + n];

  // ---- stage this half's image rows (128 b x 64 rbf) to LDS as bf16 ----
  const float* imgH = image + ((size_t)ma * A_ + half * 128) * RBF_;
  #pragma unroll
  for (int i = 0; i < 2; ++i) {
    int g = t + 512 * i;            // 0..1023 groups of 8 elems
    int r = g >> 3, c8 = g & 7;
    const float* src = imgH + r * RBF_ + c8 * 8;
    float4 v0 = *(const float4*)(src);
    float4 v1 = *(const float4*)(src + 4);
    uint4 pk;
    pk.x = pack2bf(v0.x, v0.y);
    pk.y = pack2bf(v0.z, v0.w);
    pk.z = pack2bf(v1.x, v1.y);
    pk.w = pack2bf(v1.z, v1.w);
    *(uint4*)&sA[r * 72 + c8 * 8] = pk;
  }
  // ---- stage vectors (128 b x 3) to LDS ----
  if (t < 384) sV[t] = vectors[((size_t)ma * A_ + half * 128) * 3 + t];

  // ---- running base pointers (advanced by constants; loads use imm offs) ----
  const int b0q = half * 128 + quad * 4;                      // first tile's b
  const float* p0c = feat0 + (size_t)(m * A_ + b0q) * F_ + f;       // feat0 col
  const float* p1c = feat1 + ((size_t)(m * A_ + b0q) * F_ + f) * 3; // feat1 col
  const float* svc = &sV[quad * 4 * 3];                       // this quad's v
  const unsigned short* aBc = &sA[n * 72 + quad * 8];         // a-frag base

  // single-buffer-pair operands, one-body-ahead prefetch (R8 pattern)
  float gx[2][4], gy[2][4], gz[2][4];
  float pA = 0.f, pB0 = 0.f, pB1 = 0.f, pB2 = 0.f;

  // PF: loads from running pointers with immediate offsets, then advance
#define PF(BUF) { \
    if (tag <= 1) { \
      _Pragma("unroll") \
      for (int r = 0; r < 4; ++r) gx[BUF][r] = p0c[r * F_]; \
    } else { \
      _Pragma("unroll") \
      for (int r = 0; r < 4; ++r) { \
        f32x3 v = *(const f32x3*)(p1c + r * (F_ * 3)); \
        gx[BUF][r] = v[0]; gy[BUF][r] = v[1]; gz[BUF][r] = v[2]; \
      } \
    } \
    p0c += 16 * F_; p1c += 16 * F_ * 3; }

#define BODY(AOFF, SOFF, GX, GY, GZ) { \
    const bf16x8 a0 = *(const bf16x8*)(aBc + (AOFF)); \
    const bf16x8 a1 = *(const bf16x8*)(aBc + (AOFF) + 32); \
    f32x4 acc = {bc, bc, bc, bc}; \
    acc = __builtin_amdgcn_mfma_f32_16x16x32_bf16(a0, w0, acc, 0, 0, 0); \
    acc = __builtin_amdgcn_mfma_f32_16x16x32_bf16(a1, w1, acc, 0, 0, 0); \
    if (tag == 0) {            /* out_0x0_0 */ \
      _Pragma("unroll") \
      for (int r = 0; r < 4; ++r) pA += acc[r] * GX[r]; \
    } else if (tag == 1) {     /* out_0x1_1 = v * (R*feat0) */ \
      _Pragma("unroll") \
      for (int r = 0; r < 4; ++r) { \
        const float s = acc[r] * GX[r]; \
        pB0 += svc[(SOFF) + r * 3 + 0] * s; \
        pB1 += svc[(SOFF) + r * 3 + 1] * s; \
        pB2 += svc[(SOFF) + r * 3 + 2] * s; \
      } \
    } else if (tag == 2) {     /* out_1x0_1 = R * feat1 */ \
      _Pragma("unroll") \
      for (int r = 0; r < 4; ++r) { \
        const float Rr = acc[r]; \
        pB0 += Rr * GX[r]; pB1 += Rr * GY[r]; pB2 += Rr * GZ[r]; \
      } \
    } else {                   /* out_1x1_0 (dot) + out_1x1_1 (cross) */ \
      _Pragma("unroll") \
      for (int r = 0; r < 4; ++r) { \
        const float Rr = acc[r]; \
        const float ax = GX[r], ay = GY[r], az = GZ[r]; \
        const float vx = svc[(SOFF) + r * 3 + 0]; \
        const float vy = svc[(SOFF) + r * 3 + 1]; \
        const float vz = svc[(SOFF) + r * 3 + 2]; \
        float d = vx * ax; d = fmaf(vy, ay, d); d = fmaf(vz, az, d); \
        pA = fmaf(Rr, d, pA); \
        float c0 = vy * az; c0 = fmaf(-vz, ay, c0); pB0 = fmaf(Rr, c0, pB0); \
        float c1 = vz * ax; c1 = fmaf(-vx, az, c1); pB1 = fmaf(Rr, c1, pB1); \
        float c2 = vx * ay; c2 = fmaf(-vy, ax, c2); pB2 = fmaf(Rr, c2, pB2); \
      } \
    } }

  PF(0)                 // tile 0 operands (in flight across the barrier)
  __syncthreads();

  // 8 b-tiles: unroll-1 loop of 2 bodies; per-iter offsets are immediates
  // off a base advanced once per iteration. a-frag tile stride = 16*72 shorts
  // = 1152; sV tile stride = 48 floats.
  #pragma unroll 1
  for (int it = 0; it < 4; ++it) {
    PF(1)                                   // tile 2it+1 (one-body lead)
    BODY(0, 0, gx[0], gy[0], gz[0])         // tile 2it
    if (it < 3) PF(0)                       // tile 2it+2
    BODY(1152, 48, gx[1], gy[1], gz[1])     // tile 2it+1
    aBc += 2 * 1152;
    svc += 2 * 48;
  }

  // ---- reduce the 4 quad-copies via cross-lane butterfly, write partials ----
#define QRED(x) { x += __shfl_xor(x, 16); x += __shfl_xor(x, 32); }
  QRED(pA) QRED(pB0) QRED(pB1) QRED(pB2)
  if (quad == 0) {
    float* dst = part + ((size_t)ma * 2 + half) * 352;
    // slots (cat order): out000: f | out110: 32+f | out011: 64+f*3+d
    //                    out101: 160+f*3+d | out111: 256+f*3+d
    if (tag == 0) {
      dst[f] = pA;
    } else if (tag == 1) {
      f32x3 v = {pB0, pB1, pB2};
      *(f32x3*)&dst[64 + f * 3] = v;
    } else if (tag == 2) {
      f32x3 v = {pB0, pB1, pB2};
      *(f32x3*)&dst[160 + f * 3] = v;
    } else {
      dst[32 + f] = pA;
      f32x3 v = {pB0, pB1, pB2};
      *(f32x3*)&dst[256 + f * 3] = v;
    }
  }
}

// ---------------------------------------------------------------------------
// Epilogue: one block per (m,a), 64 threads. Sum the two halves' partials,
// then self-interaction + equivariant activation.
// ---------------------------------------------------------------------------
__global__ __launch_bounds__(64) void si_epilogue(
    const float* __restrict__ part,
    const float* __restrict__ w_si0, const float* __restrict__ w_si1,
    const float* __restrict__ b_act0, const float* __restrict__ b_act1,
    float* __restrict__ out)
{
  __shared__ float cat[352];
  const int ma = blockIdx.x;
  const int t  = threadIdx.x;
  const float* pA = part + (size_t)ma * 704;
  const float* pB = pA + 352;
  for (int s = t; s < 352; s += 64) cat[s] = pA[s] + pB[s];
  __syncthreads();

  const int outBase = ma * SI_;
  if (t < 32) {
    const float* wr = w_si0 + t * 64;
    float s = 0.f;
    #pragma unroll 8
    for (int ff = 0; ff < 64; ++ff) s += cat[ff] * wr[ff];
    s += b_act0[t];
    out[outBase + t] = sspf(s);
  } else {
    int g = t - 32;
    const float* wr = w_si1 + g * 96;
    float s0 = 0.f, s1 = 0.f, s2 = 0.f;
    #pragma unroll 8
    for (int ff = 0; ff < 96; ++ff) {
      float wv = wr[ff];
      s0 += cat[64 + ff * 3 + 0] * wv;
      s1 += cat[64 + ff * 3 + 1] * wv;
      s2 += cat[64 + ff * 3 + 2] * wv;
    }
    float n2 = s0 * s0 + s1 * s1 + s2 * s2;
    float n1 = sqrtf(fmaxf(n2, 1e-7f));     // norm_with_epsilon, EPS=1e-7
    float a1 = sspf(n1 + b_act1[g]);
    float sc = a1 / n1;
    int ob = M_ * A_ * SI_ + (outBase + g) * 3;   // o0 is 32768 floats
    out[ob + 0] = s0 * sc;
    out[ob + 1] = s1 * sc;
    out[ob + 2] = s2 * sc;
  }
}

extern "C" void kernel_launch(void* const* d_in, const int* in_sizes, int n_in,
                              void* d_out, int out_size, void* d_ws, size_t ws_size,
                              hipStream_t stream) {
  const float* image   = (const float*)d_in[0];
  const float* vectors = (const float*)d_in[1];
  const float* feat0   = (const float*)d_in[2];
  const float* feat1   = (const float*)d_in[3];
  const float* w_si0   = (const float*)d_in[20];
  const float* w_si1   = (const float*)d_in[21];
  const float* b_act0  = (const float*)d_in[22];
  const float* b_act1  = (const float*)d_in[23];
  unsigned short* wsT = (unsigned short*)d_ws;           // 128*64 bf16 = 16384 B
  float* bcw  = (float*)((char*)d_ws + 16384);           // 128 f32
  float* part = (float*)((char*)d_ws + 32768);           // 1024*2*352 f32
  float* out  = (float*)d_out;

  combine_weights<<<32, 256, 0, stream>>>(
      (const float*)d_in[4],  (const float*)d_in[5],
      (const float*)d_in[6],  (const float*)d_in[7],
      (const float*)d_in[8],  (const float*)d_in[9],
      (const float*)d_in[10], (const float*)d_in[11],
      (const float*)d_in[12], (const float*)d_in[13],
      (const float*)d_in[14], (const float*)d_in[15],
      (const float*)d_in[16], (const float*)d_in[17],
      (const float*)d_in[18], (const float*)d_in[19],
      wsT, bcw);

  conv_partial<<<2 * M_ * A_, 512, 0, stream>>>(
      image, vectors, feat0, feat1, wsT, bcw, part);

  si_epilogue<<<M_ * A_, 64, 0, stream>>>(
      part, w_si0, w_si1, b_act0, b_act1, out);
}